// Round 3
// baseline (677.969 us; speedup 1.0000x reference)
//
#include <hip/hip_runtime.h>

// Problem constants
#define B_N 4096
#define T_N 512
// Output layout (floats): final (B,T,2) | fwd_out (B,2) | noise (B,T,1)
#define FWD_OFF   (B_N * T_N * 2)        // 4194304
#define NOISE_OFF (FWD_OFF + B_N * 2)    // 4202496

#define S_SIG  (-1.4426950408889634f)   // -log2(e)
#define S_TANH (-2.8853900817779268f)   // -2*log2(e)

// act on pre-scaled accumulator: returns fma(A, rcp(1+exp2(a)), B)
// A=1,B=0  -> sigmoid(v) where a = -log2e*v
// A=2,B=-1 -> tanh(v)    where a = -2log2e*v
__device__ __forceinline__ float act_ab(float a, float A, float Bc) {
    float r = __builtin_amdgcn_rcpf(1.0f + __builtin_amdgcn_exp2f(a));
    return fmaf(A, r, Bc);
}
__device__ __forceinline__ float tanh_nat(float v) {
    return fmaf(2.0f, __builtin_amdgcn_rcpf(1.0f + __builtin_amdgcn_exp2f(v * S_TANH)), -1.0f);
}
// wave-uniform broadcast: lane -> SGPR (VALU, no DS)
__device__ __forceinline__ float rlf(float v, int lane) {
    return __int_as_float(__builtin_amdgcn_readlane(__float_as_int(v), lane));
}

typedef unsigned int uv2 __attribute__((ext_vector_type(2)));

// Gate exchange, all-VALU (no LDS). Input: per-lane gate activation `a`,
// 16-lane rows ordered {i, f, g, o} (row = l>>4, unit slot = l&15).
// v_permlane32_swap(vdst,vsrc): vdst.hi32 <-> vsrc.lo32.
// v_permlane16_swap(vdst,vsrc): vdst.odd-rows <-> vsrc.even-rows.
// Output: iv,fv,gv,ov of this lane's unit slot, on every lane. 3 instrs.
__device__ __forceinline__ void gate_xchg(float a, float& iv, float& fv, float& gv, float& ov) {
    unsigned au = __float_as_uint(a);
    uv2 p = __builtin_amdgcn_permlane32_swap(au, au, false, false);   // p.x rows={i,f,i,f}, p.y={g,o,g,o}
    uv2 q = __builtin_amdgcn_permlane16_swap(p.x, p.x, false, false); // q.x=i everywhere, q.y=f
    uv2 r = __builtin_amdgcn_permlane16_swap(p.y, p.y, false, false); // r.x=g, r.y=o
    iv = __uint_as_float(q.x); fv = __uint_as_float(q.y);
    gv = __uint_as_float(r.x); ov = __uint_as_float(r.y);
}

// 64 lanes per batch element (1 element/wave) -> 4096 waves = 4 waves/SIMD.
// All cross-lane traffic is VALU (permlane swaps + readlane->SGPR); ZERO LDS/DS
// in the recurrence chain. h-state lives in SGPRs; dots are v_fma(v_w, s_h, acc).
// waves_per_eu(4,4): exactly 4 waves/EU -> 128-VGPR budget (est. use ~90).
__global__ __attribute__((amdgpu_waves_per_eu(4, 4))) __launch_bounds__(256)
void fused_kernel(
    const float* __restrict__ x,
    const float* __restrict__ eWih0, const float* __restrict__ eWhh0,
    const float* __restrict__ ebih0, const float* __restrict__ ebhh0,
    const float* __restrict__ eWih1, const float* __restrict__ eWhh1,
    const float* __restrict__ ebih1, const float* __restrict__ ebhh1,
    const float* __restrict__ dWih0, const float* __restrict__ dWhh0,
    const float* __restrict__ dbih0, const float* __restrict__ dbhh0,
    const float* __restrict__ dWih1, const float* __restrict__ dWhh1,
    const float* __restrict__ dbih1, const float* __restrict__ dbhh1,
    const float* __restrict__ fcW, const float* __restrict__ fcb,
    const float* __restrict__ outW, const float* __restrict__ outb,
    float* __restrict__ out)
{
    const int tid = blockIdx.x * 256 + threadIdx.x;
    const int b   = tid >> 6;          // batch element = wave
    const int l   = threadIdx.x & 63;  // lane
    const int u   = l & 15;            // unit slot
    const int k   = l >> 4;            // gate index 0..3 = i,f,g,o

    const float sck = (k == 2) ? S_TANH : S_SIG;
    const float Ak  = (k == 2) ? 2.0f : 1.0f;
    const float Bk  = (k == 2) ? -1.0f : 0.0f;

    // =================== ENCODER (H=4), layer-pipelined ===================
    // slot s7 = u&7: s7 in 0..3 -> L0 unit s7; s7 in 4..7 -> L1 unit s7-4
    // (L1 runs one step behind L0 - legal: encoder has no h1->L0 feedback).
    // slots 8..15 shadow slots 0..7 (never read back).
    const int  s7  = u & 7;
    const int  ur  = s7 & 3;
    const bool isl1 = (s7 >= 4);
    const int  er  = k * 4 + ur;       // gate row within the 16-row layer

    const float wx = isl1 ? 0.0f : eWih0[er] * sck;                  // x weight (L0 only)
    const float eb = ((isl1 ? ebih1[er] : ebih0[er]) +
                      (isl1 ? ebhh1[er] : ebhh0[er])) * sck;
    const float* w1src = isl1 ? eWih1 : eWhh0;   // multiplies h0
    float w1[4], w2[4];                          // w2 multiplies h1 (L1 only)
#pragma unroll
    for (int j = 0; j < 4; ++j) {
        w1[j] = w1src[er * 4 + j] * sck;
        w2[j] = isl1 ? eWhh1[er * 4 + j] * sck : 0.0f;
    }

    // wave-uniform state (SGPRs): h0, h1; per-lane cell state c
    float eh0[4] = {0.f, 0.f, 0.f, 0.f};
    float eh1[4] = {0.f, 0.f, 0.f, 0.f};
    float c = 0.f, hu = 0.f;

    auto ebody = [&](float xc) {
        // unified gate row: wx*x + w1.h0 + w2.h1 + b  (two chains for latency)
        float aa = fmaf(wx, xc, eb);
        float ab = 0.f;
        aa = fmaf(w1[0], eh0[0], aa); ab = fmaf(w1[1], eh0[1], ab);
        aa = fmaf(w1[2], eh0[2], aa); ab = fmaf(w1[3], eh0[3], ab);
        aa = fmaf(w2[0], eh1[0], aa); ab = fmaf(w2[1], eh1[1], ab);
        aa = fmaf(w2[2], eh1[2], aa); ab = fmaf(w2[3], eh1[3], ab);
        float a = act_ab(aa + ab, Ak, Bk);
        float iv, fv, gv, ov;
        gate_xchg(a, iv, fv, gv, ov);
        c = fmaf(fv, c, iv * gv);
        hu = ov * tanh_nat(c);
        // new h -> SGPRs: lanes 0..3 hold h0 units, 4..7 hold h1 units
#pragma unroll
        for (int j = 0; j < 4; ++j) eh0[j] = rlf(hu, j);
#pragma unroll
        for (int j = 0; j < 4; ++j) eh1[j] = rlf(hu, 4 + j);
    };

    const float4* __restrict__ xq4 = (const float4*)(x + (long)b * T_N);
    float4 xq = xq4[0];
    float4 xn = xq4[1];

    ebody(xq.x);                       // s=0: L0 -> h0(0); L1 ran a bogus step
    if (isl1) c = 0.f;                 // neutralize L1's bogus first step
#pragma unroll
    for (int j = 0; j < 4; ++j) eh1[j] = 0.f;
    ebody(xq.y); ebody(xq.z); ebody(xq.w);
    xq = xn;
#pragma unroll 1
    for (int tb = 1; tb < T_N / 4; ++tb) {
        xn = (tb + 1 < T_N / 4) ? xq4[tb + 1] : xq;
        ebody(xq.x); ebody(xq.y); ebody(xq.z); ebody(xq.w);
        xq = xn;
    }
    // L0 final: h0(511) in eh0, c0 on L0 lanes. L1 is at h1(510):
    // save L0 finals, run one more body for h1(511)/c1(511).
    float eh0f[4];
#pragma unroll
    for (int j = 0; j < 4; ++j) eh0f[j] = eh0[j];
    const float c0sav = c;
    ebody(0.f);                        // only the L1 half is meaningful
    // eh1 = h1 final (uniform); c on lanes s7=4..7 = c1 final

    const float c0u0 = rlf(c0sav, 0), c0u1 = rlf(c0sav, 1);
    const float c0u2 = rlf(c0sav, 2), c0u3 = rlf(c0sav, 3);
    const float c1u0 = rlf(c, 4), c1u1 = rlf(c, 5);
    const float c1u2 = rlf(c, 6), c1u3 = rlf(c, 7);

    // fwd_out = h1 @ fc_W.T + fc_b (uniform on all lanes)
    float fw0 = fcb[0], fw1 = fcb[1];
#pragma unroll
    for (int j = 0; j < 4; ++j) {
        fw0 = fmaf(fcW[j], eh1[j], fw0);
        fw1 = fmaf(fcW[4 + j], eh1[j], fw1);
    }
    if (l == 0) {
        out[FWD_OFF + b * 2 + 0] = fw0;
        out[FWD_OFF + b * 2 + 1] = fw1;
    }

    __builtin_amdgcn_sched_barrier(0);  // keep decoder weight loads out of the encoder

    // =================== DECODER (H=10), gate-row-parallel ===================
    // lane (k, u): gate k of unit u (u in 0..9; slots 10..15 shadow unit 9).
    const int uc = (u < 10) ? u : 9;
    const int r  = k * 10 + uc;

    const float wih0r = dWih0[r] * sck;
    const float b0r = (dbih0[r] + dbhh0[r]) * sck;
    const float b1r = (dbih1[r] + dbhh1[r]) * sck;
    float whh0r[10], wih1r[10], whh1r[10];
#pragma unroll
    for (int j = 0; j < 10; ++j) {
        whh0r[j] = dWhh0[r * 10 + j] * sck;
        wih1r[j] = dWih1[r * 10 + j] * sck;
        whh1r[j] = dWhh1[r * 10 + j] * sck;
    }
    float outwr[10];
#pragma unroll
    for (int j = 0; j < 10; ++j) outwr[j] = outW[j];
    const float outb0 = outb[0];

    // Initial decoder state: encoder finals padded 4 -> 10 with zeros.
    float sh0[10], sh1[10];   // wave-uniform h (SGPRs)
#pragma unroll
    for (int j = 0; j < 10; ++j) {
        sh0[j] = (j < 4) ? eh0f[j] : 0.f;
        sh1[j] = (j < 4) ? eh1[j] : 0.f;
    }
    // per-lane cell state for this lane's unit slot (replicated across gates)
    float dc0 = (u == 0) ? c0u0 : (u == 1) ? c0u1 : (u == 2) ? c0u2 : (u == 3) ? c0u3 : 0.f;
    float dc1 = (u == 0) ? c1u0 : (u == 1) ? c1u1 : (u == 2) ? c1u2 : (u == 3) ? c1u3 : 0.f;

    float my_noise = 0.f;

#pragma unroll 1
    for (int t = 0; t < T_N; ++t) {
        // L1 partial from previous h1 (independent of the L0 chain)
        float pa = b1r, pb = 0.f;
#pragma unroll
        for (int j = 0; j < 5; ++j) {
            pa = fmaf(whh1r[2 * j],     sh1[2 * j],     pa);
            pb = fmaf(whh1r[2 * j + 1], sh1[2 * j + 1], pb);
        }
        const float inp = sh1[0];

        // L0 gate row (one per lane)
        float ga = fmaf(wih0r, inp, b0r), gb = 0.f;
#pragma unroll
        for (int j = 0; j < 5; ++j) {
            ga = fmaf(whh0r[2 * j],     sh0[2 * j],     ga);
            gb = fmaf(whh0r[2 * j + 1], sh0[2 * j + 1], gb);
        }
        float a = act_ab(ga + gb, Ak, Bk);
        float iv, fv, gv, ov;
        gate_xchg(a, iv, fv, gv, ov);
        dc0 = fmaf(fv, dc0, iv * gv);
        const float h0u = ov * tanh_nat(dc0);
#pragma unroll
        for (int j = 0; j < 10; ++j) sh0[j] = rlf(h0u, j);

        // L1 gate row: add the h0-dependent half
#pragma unroll
        for (int j = 0; j < 5; ++j) {
            pa = fmaf(wih1r[2 * j],     sh0[2 * j],     pa);
            pb = fmaf(wih1r[2 * j + 1], sh0[2 * j + 1], pb);
        }
        a = act_ab(pa + pb, Ak, Bk);
        gate_xchg(a, iv, fv, gv, ov);
        dc1 = fmaf(fv, dc1, iv * gv);
        const float h1u = ov * tanh_nat(dc1);
#pragma unroll
        for (int j = 0; j < 10; ++j) sh1[j] = rlf(h1u, j);

        // noise_t = dec_out . out_W + out_b (uniform on all lanes)
        float na = outb0, nb = 0.f;
#pragma unroll
        for (int j = 0; j < 5; ++j) {
            na = fmaf(outwr[2 * j],     sh1[2 * j],     na);
            nb = fmaf(outwr[2 * j + 1], sh1[2 * j + 1], nb);
        }
        const float nz = na + nb;

        // lane l keeps t with t%64==l; flush coalesced every 64 steps
        my_noise = ((t & 63) == l) ? nz : my_noise;
        if ((t & 63) == 63) {
            const int idx = b * T_N + (t - 63) + l;
            out[NOISE_OFF + idx] = my_noise;
            float2 fin;
            fin.x = my_noise + fw0;
            fin.y = my_noise + fw1;
            ((float2*)out)[idx] = fin;
        }
    }
}

extern "C" void kernel_launch(void* const* d_in, const int* in_sizes, int n_in,
                              void* d_out, int out_size, void* d_ws, size_t ws_size,
                              hipStream_t stream) {
    const float* x     = (const float*)d_in[0];
    // d_in[1] = context (unused by the reference)
    const float* eWih0 = (const float*)d_in[2];
    const float* eWhh0 = (const float*)d_in[3];
    const float* ebih0 = (const float*)d_in[4];
    const float* ebhh0 = (const float*)d_in[5];
    const float* eWih1 = (const float*)d_in[6];
    const float* eWhh1 = (const float*)d_in[7];
    const float* ebih1 = (const float*)d_in[8];
    const float* ebhh1 = (const float*)d_in[9];
    const float* dWih0 = (const float*)d_in[10];
    const float* dWhh0 = (const float*)d_in[11];
    const float* dbih0 = (const float*)d_in[12];
    const float* dbhh0 = (const float*)d_in[13];
    const float* dWih1 = (const float*)d_in[14];
    const float* dWhh1 = (const float*)d_in[15];
    const float* dbih1 = (const float*)d_in[16];
    const float* dbhh1 = (const float*)d_in[17];
    const float* fcW   = (const float*)d_in[18];
    const float* fcb   = (const float*)d_in[19];
    const float* outW  = (const float*)d_in[20];
    const float* outb  = (const float*)d_in[21];

    float* out = (float*)d_out;

    // 4096 elems x 64 lanes = 262144 threads = 4096 waves = 4 waves/SIMD
    fused_kernel<<<dim3((B_N * 64) / 256), dim3(256), 0, stream>>>(
        x, eWih0, eWhh0, ebih0, ebhh0, eWih1, eWhh1, ebih1, ebhh1,
        dWih0, dWhh0, dbih0, dbhh0, dWih1, dWhh1, dbih1, dbhh1,
        fcW, fcb, outW, outb, out);
}

// Round 6
// 393.310 us; speedup vs baseline: 1.7238x; 1.7238x over previous
//
#include <hip/hip_runtime.h>

// Problem constants
#define B_N 4096
#define T_N 512
// Output layout (floats): final (B,T,2) | fwd_out (B,2) | noise (B,T,1)
#define FWD_OFF   (B_N * T_N * 2)        // 4194304
#define NOISE_OFF (FWD_OFF + B_N * 2)    // 4202496

#define S_SIG  (-1.4426950408889634f)   // -log2(e)
#define S_TANH (-2.8853900817779268f)   // -2*log2(e)

// act on pre-scaled accumulator: returns fma(A, rcp(1+exp2(a)), B)
// A=1,B=0  -> sigmoid(v) where a = -log2e*v
// A=2,B=-1 -> tanh(v)    where a = -2log2e*v
__device__ __forceinline__ float act_ab(float a, float A, float Bc) {
    float r = __builtin_amdgcn_rcpf(1.0f + __builtin_amdgcn_exp2f(a));
    return fmaf(A, r, Bc);
}
__device__ __forceinline__ float sig_acc(float a) {
    return __builtin_amdgcn_rcpf(1.0f + __builtin_amdgcn_exp2f(a));
}
__device__ __forceinline__ float tanh_acc(float a) {
    return fmaf(2.0f, __builtin_amdgcn_rcpf(1.0f + __builtin_amdgcn_exp2f(a)), -1.0f);
}
__device__ __forceinline__ float tanh_nat(float v) {
    return tanh_acc(v * S_TANH);
}

// ---- DPP cross-lane (all-VALU, zero DS in the kernel) ----
// ROW_ROR:N (0x120+N): dst lane i <- src lane (i-N)&15 within each 16-lane row
//   (same direction as row_shr: the prefix-sum idiom `row_shr:1` adds lane i-1).
// ROW_NEWBCAST:J (0x150+J, gfx90a+): dst lane i <- src lane J of its 16-lane row
template<int CTRL>
__device__ __forceinline__ float dppf(float v) {
    return __int_as_float(__builtin_amdgcn_update_dpp(
        __float_as_int(v), __float_as_int(v), CTRL, 0xF, 0xF, false));
}
// broadcast lane j (j=0..3) of each 16-lane row to the whole row
__device__ __forceinline__ void bcast4(float v, float* d) {
    d[0] = dppf<0x150>(v); d[1] = dppf<0x151>(v);
    d[2] = dppf<0x152>(v); d[3] = dppf<0x153>(v);
}
// broadcast lanes 0..9 of each 16-lane row to the whole row
__device__ __forceinline__ void bcast10(float v, float* d) {
    d[0] = dppf<0x150>(v); d[1] = dppf<0x151>(v);
    d[2] = dppf<0x152>(v); d[3] = dppf<0x153>(v);
    d[4] = dppf<0x154>(v); d[5] = dppf<0x155>(v);
    d[6] = dppf<0x156>(v); d[7] = dppf<0x157>(v);
    d[8] = dppf<0x158>(v); d[9] = dppf<0x159>(v);
}

// Round-0 structure (best measured: 400 us, chain-bound at 49% VALUBusy) with
// every __shfl (ds_bpermute, ~30-50cyc DS round-trip) replaced by DPP VALU ops.
// 16 lanes/elem, 4 elems/wave: each wave-instruction serves 4 batch elements
// (the instruction-count optimum across rounds 0/2/3). 1 wave/SIMD.
__global__ __attribute__((amdgpu_waves_per_eu(1, 1))) __launch_bounds__(256)
void fused_kernel(
    const float* __restrict__ x,
    const float* __restrict__ eWih0, const float* __restrict__ eWhh0,
    const float* __restrict__ ebih0, const float* __restrict__ ebhh0,
    const float* __restrict__ eWih1, const float* __restrict__ eWhh1,
    const float* __restrict__ ebih1, const float* __restrict__ ebhh1,
    const float* __restrict__ dWih0, const float* __restrict__ dWhh0,
    const float* __restrict__ dbih0, const float* __restrict__ dbhh0,
    const float* __restrict__ dWih1, const float* __restrict__ dWhh1,
    const float* __restrict__ dbih1, const float* __restrict__ dbhh1,
    const float* __restrict__ fcW, const float* __restrict__ fcb,
    const float* __restrict__ outW, const float* __restrict__ outb,
    float* __restrict__ out)
{
    const int tid  = blockIdx.x * 256 + threadIdx.x;
    const int b    = tid >> 4;     // batch element
    const int lane = tid & 15;     // 16 lanes per element (= one DPP row)

    // =================== ENCODER: gate-row-parallel (H=4) ===================
    // lane = k*4 + u : k in {i,f,g,o}, u = unit. Row r = lane of the (16,*) mats.
    const int u4 = lane & 3;
    const int kk = lane >> 2;
    const float sc = (kk == 2) ? S_TANH : S_SIG;
    const float Ak = (kk == 2) ? 2.0f : 1.0f;
    const float Bk = (kk == 2) ? -1.0f : 0.0f;

    float h0v[4] = {0.f, 0.f, 0.f, 0.f};
    float h1v[4] = {0.f, 0.f, 0.f, 0.f};
    float c0 = 0.f, c1 = 0.f;
    float fw0, fw1;

    {
        const int r = lane;
        float ew0 = eWih0[r] * sc;
        float eb0 = (ebih0[r] + ebhh0[r]) * sc;
        float eb1 = (ebih1[r] + ebhh1[r]) * sc;
        float ewh0[4], ewi1[4], ewh1[4];
#pragma unroll
        for (int j = 0; j < 4; ++j) {
            ewh0[j] = eWhh0[r * 4 + j] * sc;
            ewi1[j] = eWih1[r * 4 + j] * sc;
            ewh1[j] = eWhh1[r * 4 + j] * sc;
        }

        const float4* __restrict__ xq4 = (const float4*)(x + (long)b * T_N);
        float4 xq = xq4[0];

        auto estep = [&](float xc) {
            // L1 partial from previous h1 (independent of L0 chain)
            float p = eb1;
#pragma unroll
            for (int j = 0; j < 4; ++j) p = fmaf(ewh1[j], h1v[j], p);

            // L0 gate-row dot
            float g = fmaf(ew0, xc, eb0);
#pragma unroll
            for (int j = 0; j < 4; ++j) g = fmaf(ewh0[j], h0v[j], g);
            float gate = act_ab(g, Ak, Bk);   // one exp2+rcp for all 16 gate rows
            // gate combine via DPP row rotate (src lane = (i-N)&15):
            // on lanes 0..3 (i=u4): ror:12 -> i+4 (f), ror:8 -> i+8 (g), ror:4 -> i+12 (o)
            float fv = dppf<0x12C>(gate);     // row_ror:12 -> f row
            float gv = dppf<0x128>(gate);     // row_ror:8  -> g row
            float ov = dppf<0x124>(gate);     // row_ror:4  -> o row
            c0 = fmaf(fv, c0, gate * gv);     // valid on lanes 0..3 (gate = i there)
            float h0u = ov * tanh_nat(c0);
            bcast4(h0u, h0v);                 // row_newbcast:0..3

            // L1 gate-row dot (post-broadcast half)
            float q = 0.f;
#pragma unroll
            for (int j = 0; j < 4; ++j) q = fmaf(ewi1[j], h0v[j], q);
            float g1 = p + q;
            float gate1 = act_ab(g1, Ak, Bk);
            fv = dppf<0x12C>(gate1);
            gv = dppf<0x128>(gate1);
            ov = dppf<0x124>(gate1);
            c1 = fmaf(fv, c1, gate1 * gv);
            float h1u = ov * tanh_nat(c1);
            bcast4(h1u, h1v);
        };

        for (int tb = 0; tb < T_N / 4; ++tb) {
            float4 xn = (tb + 1 < T_N / 4) ? xq4[tb + 1] : xq;  // prefetch
            estep(xq.x); estep(xq.y); estep(xq.z); estep(xq.w);
            xq = xn;
        }

        // fwd_out = h1 @ fc_W.T + fc_b   (computed uniformly on all lanes)
        fw0 = fcb[0];
        fw1 = fcb[1];
#pragma unroll
        for (int j = 0; j < 4; ++j) {
            fw0 = fmaf(fcW[j], h1v[j], fw0);
            fw1 = fmaf(fcW[4 + j], h1v[j], fw1);
        }
        if (lane == 0) {
            out[FWD_OFF + b * 2 + 0] = fw0;
            out[FWD_OFF + b * 2 + 1] = fw1;
        }
    }

    // =================== DECODER: unit-parallel (H=10) ===================
    // lane = unit (0..9 active; 10..15 shadow 9). State handoff in-register:
    // encoder kept unit-u state on lane u (u<4); h vectors are replicated.
    const int uc = (lane < 10) ? lane : 9;

    float wih0r[4], b0r[4], b1r[4];
    float whh0r[4][10], wih1r[4][10], whh1r[4][10];
#pragma unroll
    for (int k = 0; k < 4; ++k) {
        const int r = k * 10 + uc;
        const float sck = (k == 2) ? S_TANH : S_SIG;
        wih0r[k] = dWih0[r] * sck;
        b0r[k] = (dbih0[r] + dbhh0[r]) * sck;
        b1r[k] = (dbih1[r] + dbhh1[r]) * sck;
#pragma unroll
        for (int j = 0; j < 10; ++j) {
            whh0r[k][j] = dWhh0[r * 10 + j] * sck;
            wih1r[k][j] = dWih1[r * 10 + j] * sck;
            whh1r[k][j] = dWhh1[r * 10 + j] * sck;
        }
    }
    float outw[10];
#pragma unroll
    for (int j = 0; j < 10; ++j) outw[j] = outW[j];
    const float outb0 = outb[0];

    // Initial decoder state: encoder finals padded 4 -> 10 with zeros
    float dh0[10], dh1[10];
#pragma unroll
    for (int j = 0; j < 10; ++j) {
        dh0[j] = (j < 4) ? h0v[j] : 0.f;
        dh1[j] = (j < 4) ? h1v[j] : 0.f;
    }
    float dc0 = (lane < 4) ? c0 : 0.f;
    float dc1 = (lane < 4) ? c1 : 0.f;

    float my_noise = 0.f;

    for (int t = 0; t < T_N; ++t) {
        const float inp = dh1[0];

        // L1 partial from previous h1 (independent of L0 chain)
        float p1[4];
#pragma unroll
        for (int k = 0; k < 4; ++k) {
            p1[k] = b1r[k];
#pragma unroll
            for (int j = 0; j < 10; ++j) p1[k] = fmaf(whh1r[k][j], dh1[j], p1[k]);
        }

        // L0 gates
        float g[4];
#pragma unroll
        for (int k = 0; k < 4; ++k) {
            g[k] = fmaf(wih0r[k], inp, b0r[k]);
#pragma unroll
            for (int j = 0; j < 10; ++j) g[k] = fmaf(whh0r[k][j], dh0[j], g[k]);
        }
        float iv = sig_acc(g[0]), fv = sig_acc(g[1]), gv = tanh_acc(g[2]), ov = sig_acc(g[3]);
        dc0 = fmaf(fv, dc0, iv * gv);
        const float h0u = ov * tanh_nat(dc0);
        bcast10(h0u, dh0);               // row_newbcast:0..9 (was 10x ds_bpermute)

        // L1 gates: separate accumulator for the post-broadcast half (latency)
#pragma unroll
        for (int k = 0; k < 4; ++k) {
            float q = 0.f;
#pragma unroll
            for (int j = 0; j < 10; ++j) q = fmaf(wih1r[k][j], dh0[j], q);
            p1[k] += q;
        }
        iv = sig_acc(p1[0]); fv = sig_acc(p1[1]); gv = tanh_acc(p1[2]); ov = sig_acc(p1[3]);
        dc1 = fmaf(fv, dc1, iv * gv);
        const float h1u = ov * tanh_nat(dc1);
        bcast10(h1u, dh1);

        // noise_t = dec_out . out_W + out_b (uniform on all 16 lanes)
        float nz = outb0;
#pragma unroll
        for (int j = 0; j < 10; ++j) nz = fmaf(outw[j], dh1[j], nz);

        // lane u keeps t with t%16==u; flush coalesced every 16 steps
        my_noise = ((t & 15) == lane) ? nz : my_noise;
        if ((t & 15) == 15) {
            const int idx = b * T_N + (t - 15) + lane;
            out[NOISE_OFF + idx] = my_noise;
            float2 fin;
            fin.x = my_noise + fw0;
            fin.y = my_noise + fw1;
            ((float2*)out)[idx] = fin;
        }
    }
}

extern "C" void kernel_launch(void* const* d_in, const int* in_sizes, int n_in,
                              void* d_out, int out_size, void* d_ws, size_t ws_size,
                              hipStream_t stream) {
    const float* x     = (const float*)d_in[0];
    // d_in[1] = context (unused by the reference)
    const float* eWih0 = (const float*)d_in[2];
    const float* eWhh0 = (const float*)d_in[3];
    const float* ebih0 = (const float*)d_in[4];
    const float* ebhh0 = (const float*)d_in[5];
    const float* eWih1 = (const float*)d_in[6];
    const float* eWhh1 = (const float*)d_in[7];
    const float* ebih1 = (const float*)d_in[8];
    const float* ebhh1 = (const float*)d_in[9];
    const float* dWih0 = (const float*)d_in[10];
    const float* dWhh0 = (const float*)d_in[11];
    const float* dbih0 = (const float*)d_in[12];
    const float* dbhh0 = (const float*)d_in[13];
    const float* dWih1 = (const float*)d_in[14];
    const float* dWhh1 = (const float*)d_in[15];
    const float* dbih1 = (const float*)d_in[16];
    const float* dbhh1 = (const float*)d_in[17];
    const float* fcW   = (const float*)d_in[18];
    const float* fcb   = (const float*)d_in[19];
    const float* outW  = (const float*)d_in[20];
    const float* outb  = (const float*)d_in[21];

    float* out = (float*)d_out;

    // 4096 elems x 16 lanes = 65536 threads = 1024 waves = 1 wave/SIMD
    fused_kernel<<<dim3((B_N * 16) / 256), dim3(256), 0, stream>>>(
        x, eWih0, eWhh0, ebih0, ebhh0, eWih1, eWhh1, ebih1, ebhh1,
        dWih0, dWhh0, dbih0, dbhh0, dWih1, dWhh1, dbih1, dbhh1,
        fcW, fcb, outW, outb, out);
}

// Round 7
// 365.434 us; speedup vs baseline: 1.8552x; 1.0763x over previous
//
#include <hip/hip_runtime.h>

// Problem constants
#define B_N 4096
#define T_N 512
// Output layout (floats): final (B,T,2) | fwd_out (B,2) | noise (B,T,1)
#define FWD_OFF   (B_N * T_N * 2)        // 4194304
#define NOISE_OFF (FWD_OFF + B_N * 2)    // 4202496

#define S_SIG  (-1.4426950408889634f)   // -log2(e)
#define S_TANH (-2.8853900817779268f)   // -2*log2(e)

typedef float v2f __attribute__((ext_vector_type(2)));
__device__ __forceinline__ v2f mkv2(float a, float b) { v2f r; r.x = a; r.y = b; return r; }

// packed fp32 fma: d = a*b + c elementwise (v_pk_fma_f32) — halves dot-product issue count
__device__ __forceinline__ v2f pk_fma(v2f a, v2f b, v2f c) {
    v2f d;
    asm("v_pk_fma_f32 %0, %1, %2, %3" : "=v"(d) : "v"(a), "v"(b), "v"(c));
    return d;
}

// act on pre-scaled accumulator: returns fma(A, rcp(1+exp2(a)), B)
// A=1,B=0  -> sigmoid(v) where a = -log2e*v
// A=2,B=-1 -> tanh(v)    where a = -2log2e*v
__device__ __forceinline__ float act_ab(float a, float A, float Bc) {
    float r = __builtin_amdgcn_rcpf(1.0f + __builtin_amdgcn_exp2f(a));
    return fmaf(A, r, Bc);
}
__device__ __forceinline__ float sig_acc(float a) {
    return __builtin_amdgcn_rcpf(1.0f + __builtin_amdgcn_exp2f(a));
}
__device__ __forceinline__ float tanh_acc(float a) {
    return fmaf(2.0f, __builtin_amdgcn_rcpf(1.0f + __builtin_amdgcn_exp2f(a)), -1.0f);
}
__device__ __forceinline__ float tanh_nat(float v) {
    return tanh_acc(v * S_TANH);
}

// ---- DPP cross-lane (all-VALU, zero DS in the kernel) ----
// ROW_ROR:N (0x120+N): dst lane i <- src lane (i-N)&15 within each 16-lane row
// ROW_NEWBCAST:J (0x150+J, gfx90a+): dst lane i <- src lane J of its 16-lane row
template<int CTRL>
__device__ __forceinline__ float dppf(float v) {
    return __int_as_float(__builtin_amdgcn_update_dpp(
        __float_as_int(v), __float_as_int(v), CTRL, 0xF, 0xF, false));
}

// Round-6 structure (measured 337.7 us steady, VALUBusy 71.5%) + v_pk_fma_f32
// packing of every H-dot (decoder: 134 scalar fma -> ~64 pk + 4 scalar).
// 16 lanes/elem, 4 elems/wave, 1 wave/SIMD, all cross-lane via DPP.
__global__ __attribute__((amdgpu_waves_per_eu(1, 1))) __launch_bounds__(256)
void fused_kernel(
    const float* __restrict__ x,
    const float* __restrict__ eWih0, const float* __restrict__ eWhh0,
    const float* __restrict__ ebih0, const float* __restrict__ ebhh0,
    const float* __restrict__ eWih1, const float* __restrict__ eWhh1,
    const float* __restrict__ ebih1, const float* __restrict__ ebhh1,
    const float* __restrict__ dWih0, const float* __restrict__ dWhh0,
    const float* __restrict__ dbih0, const float* __restrict__ dbhh0,
    const float* __restrict__ dWih1, const float* __restrict__ dWhh1,
    const float* __restrict__ dbih1, const float* __restrict__ dbhh1,
    const float* __restrict__ fcW, const float* __restrict__ fcb,
    const float* __restrict__ outW, const float* __restrict__ outb,
    float* __restrict__ out)
{
    const int tid  = blockIdx.x * 256 + threadIdx.x;
    const int b    = tid >> 4;     // batch element
    const int lane = tid & 15;     // 16 lanes per element (= one DPP row)

    // =================== ENCODER: gate-row-parallel (H=4) ===================
    const int kk = lane >> 2;
    const float sc = (kk == 2) ? S_TANH : S_SIG;
    const float Ak = (kk == 2) ? 2.0f : 1.0f;
    const float Bk = (kk == 2) ? -1.0f : 0.0f;

    v2f h0p[2] = {mkv2(0.f, 0.f), mkv2(0.f, 0.f)};
    v2f h1p[2] = {mkv2(0.f, 0.f), mkv2(0.f, 0.f)};
    float c0 = 0.f, c1 = 0.f;
    float fw0, fw1;

    {
        const int r = lane;
        float ew0 = eWih0[r] * sc;
        float eb0 = (ebih0[r] + ebhh0[r]) * sc;
        float eb1 = (ebih1[r] + ebhh1[r]) * sc;
        v2f ewh0p[2], ewi1p[2], ewh1p[2];
#pragma unroll
        for (int j = 0; j < 2; ++j) {
            ewh0p[j] = mkv2(eWhh0[r * 4 + 2 * j], eWhh0[r * 4 + 2 * j + 1]) * sc;
            ewi1p[j] = mkv2(eWih1[r * 4 + 2 * j], eWih1[r * 4 + 2 * j + 1]) * sc;
            ewh1p[j] = mkv2(eWhh1[r * 4 + 2 * j], eWhh1[r * 4 + 2 * j + 1]) * sc;
        }

        const float4* __restrict__ xq4 = (const float4*)(x + (long)b * T_N);
        float4 xq = xq4[0];

        auto estep = [&](float xc) {
            // L1 partial from previous h1 (independent of L0 chain)
            v2f pp = pk_fma(ewh1p[0], h1p[0], mkv2(eb1, 0.f));
            pp = pk_fma(ewh1p[1], h1p[1], pp);

            // L0 gate-row dot
            v2f gg = pk_fma(ewh0p[0], h0p[0], mkv2(fmaf(ew0, xc, eb0), 0.f));
            gg = pk_fma(ewh0p[1], h0p[1], gg);
            float gate = act_ab(gg.x + gg.y, Ak, Bk);
            // gate combine via DPP row rotate (src lane = (i-N)&15):
            // on lanes 0..3: ror:12 -> i+4 (f), ror:8 -> i+8 (g), ror:4 -> i+12 (o)
            float fv = dppf<0x12C>(gate);
            float gv = dppf<0x128>(gate);
            float ov = dppf<0x124>(gate);
            c0 = fmaf(fv, c0, gate * gv);     // valid on lanes 0..3 (gate = i there)
            float h0u = ov * tanh_nat(c0);
            h0p[0].x = dppf<0x150>(h0u); h0p[0].y = dppf<0x151>(h0u);
            h0p[1].x = dppf<0x152>(h0u); h0p[1].y = dppf<0x153>(h0u);

            // L1 gate-row dot (post-broadcast half)
            v2f qq = pk_fma(ewi1p[0], h0p[0], pp);
            qq = pk_fma(ewi1p[1], h0p[1], qq);
            float gate1 = act_ab(qq.x + qq.y, Ak, Bk);
            fv = dppf<0x12C>(gate1);
            gv = dppf<0x128>(gate1);
            ov = dppf<0x124>(gate1);
            c1 = fmaf(fv, c1, gate1 * gv);
            float h1u = ov * tanh_nat(c1);
            h1p[0].x = dppf<0x150>(h1u); h1p[0].y = dppf<0x151>(h1u);
            h1p[1].x = dppf<0x152>(h1u); h1p[1].y = dppf<0x153>(h1u);
        };

        for (int tb = 0; tb < T_N / 4; ++tb) {
            float4 xn = (tb + 1 < T_N / 4) ? xq4[tb + 1] : xq;  // prefetch
            estep(xq.x); estep(xq.y); estep(xq.z); estep(xq.w);
            xq = xn;
        }

        // fwd_out = h1 @ fc_W.T + fc_b   (computed uniformly on all lanes)
        fw0 = fcb[0];
        fw1 = fcb[1];
        fw0 = fmaf(fcW[0], h1p[0].x, fw0); fw0 = fmaf(fcW[1], h1p[0].y, fw0);
        fw0 = fmaf(fcW[2], h1p[1].x, fw0); fw0 = fmaf(fcW[3], h1p[1].y, fw0);
        fw1 = fmaf(fcW[4], h1p[0].x, fw1); fw1 = fmaf(fcW[5], h1p[0].y, fw1);
        fw1 = fmaf(fcW[6], h1p[1].x, fw1); fw1 = fmaf(fcW[7], h1p[1].y, fw1);
        if (lane == 0) {
            out[FWD_OFF + b * 2 + 0] = fw0;
            out[FWD_OFF + b * 2 + 1] = fw1;
        }
    }

    // =================== DECODER: unit-parallel (H=10) ===================
    // lane = unit (0..9 active; 10..15 shadow 9). All dots packed as v2f.
    const int uc = (lane < 10) ? lane : 9;

    float wih0r[4], b0r[4], b1r[4];
    v2f whh0p[4][5], wih1p[4][5], whh1p[4][5];
#pragma unroll
    for (int k = 0; k < 4; ++k) {
        const int r = k * 10 + uc;
        const float sck = (k == 2) ? S_TANH : S_SIG;
        wih0r[k] = dWih0[r] * sck;
        b0r[k] = (dbih0[r] + dbhh0[r]) * sck;
        b1r[k] = (dbih1[r] + dbhh1[r]) * sck;
#pragma unroll
        for (int j = 0; j < 5; ++j) {
            whh0p[k][j] = mkv2(dWhh0[r * 10 + 2 * j], dWhh0[r * 10 + 2 * j + 1]) * sck;
            wih1p[k][j] = mkv2(dWih1[r * 10 + 2 * j], dWih1[r * 10 + 2 * j + 1]) * sck;
            whh1p[k][j] = mkv2(dWhh1[r * 10 + 2 * j], dWhh1[r * 10 + 2 * j + 1]) * sck;
        }
    }
    v2f outwp[5];
#pragma unroll
    for (int j = 0; j < 5; ++j) outwp[j] = mkv2(outW[2 * j], outW[2 * j + 1]);
    const float outb0 = outb[0];

    // Initial decoder state: encoder finals padded 4 -> 10 with zeros
    v2f dh0p[5], dh1p[5];
    dh0p[0] = h0p[0]; dh0p[1] = h0p[1];
    dh1p[0] = h1p[0]; dh1p[1] = h1p[1];
#pragma unroll
    for (int j = 2; j < 5; ++j) { dh0p[j] = mkv2(0.f, 0.f); dh1p[j] = mkv2(0.f, 0.f); }
    float dc0 = (lane < 4) ? c0 : 0.f;
    float dc1 = (lane < 4) ? c1 : 0.f;

    float my_noise = 0.f;

    for (int t = 0; t < T_N; ++t) {
        const float inp = dh1p[0].x;

        // L1 partial from previous h1 (independent of L0 chain)
        v2f p1[4];
#pragma unroll
        for (int k = 0; k < 4; ++k) {
            p1[k] = pk_fma(whh1p[k][0], dh1p[0], mkv2(b1r[k], 0.f));
#pragma unroll
            for (int j = 1; j < 5; ++j) p1[k] = pk_fma(whh1p[k][j], dh1p[j], p1[k]);
        }

        // L0 gates
        v2f g2[4];
#pragma unroll
        for (int k = 0; k < 4; ++k) {
            g2[k] = pk_fma(whh0p[k][0], dh0p[0], mkv2(fmaf(wih0r[k], inp, b0r[k]), 0.f));
#pragma unroll
            for (int j = 1; j < 5; ++j) g2[k] = pk_fma(whh0p[k][j], dh0p[j], g2[k]);
        }
        float iv = sig_acc(g2[0].x + g2[0].y);
        float fv = sig_acc(g2[1].x + g2[1].y);
        float gv = tanh_acc(g2[2].x + g2[2].y);
        float ov = sig_acc(g2[3].x + g2[3].y);
        dc0 = fmaf(fv, dc0, iv * gv);
        const float h0u = ov * tanh_nat(dc0);
        dh0p[0].x = dppf<0x150>(h0u); dh0p[0].y = dppf<0x151>(h0u);
        dh0p[1].x = dppf<0x152>(h0u); dh0p[1].y = dppf<0x153>(h0u);
        dh0p[2].x = dppf<0x154>(h0u); dh0p[2].y = dppf<0x155>(h0u);
        dh0p[3].x = dppf<0x156>(h0u); dh0p[3].y = dppf<0x157>(h0u);
        dh0p[4].x = dppf<0x158>(h0u); dh0p[4].y = dppf<0x159>(h0u);

        // L1 gates: accumulate the post-broadcast half into p1
#pragma unroll
        for (int k = 0; k < 4; ++k) {
#pragma unroll
            for (int j = 0; j < 5; ++j) p1[k] = pk_fma(wih1p[k][j], dh0p[j], p1[k]);
        }
        iv = sig_acc(p1[0].x + p1[0].y);
        fv = sig_acc(p1[1].x + p1[1].y);
        gv = tanh_acc(p1[2].x + p1[2].y);
        ov = sig_acc(p1[3].x + p1[3].y);
        dc1 = fmaf(fv, dc1, iv * gv);
        const float h1u = ov * tanh_nat(dc1);
        dh1p[0].x = dppf<0x150>(h1u); dh1p[0].y = dppf<0x151>(h1u);
        dh1p[1].x = dppf<0x152>(h1u); dh1p[1].y = dppf<0x153>(h1u);
        dh1p[2].x = dppf<0x154>(h1u); dh1p[2].y = dppf<0x155>(h1u);
        dh1p[3].x = dppf<0x156>(h1u); dh1p[3].y = dppf<0x157>(h1u);
        dh1p[4].x = dppf<0x158>(h1u); dh1p[4].y = dppf<0x159>(h1u);

        // noise_t = dec_out . out_W + out_b (uniform on all 16 lanes)
        v2f na = pk_fma(outwp[0], dh1p[0], mkv2(outb0, 0.f));
#pragma unroll
        for (int j = 1; j < 5; ++j) na = pk_fma(outwp[j], dh1p[j], na);
        const float nz = na.x + na.y;

        // lane u keeps t with t%16==u; flush coalesced every 16 steps
        my_noise = ((t & 15) == lane) ? nz : my_noise;
        if ((t & 15) == 15) {
            const int idx = b * T_N + (t - 15) + lane;
            out[NOISE_OFF + idx] = my_noise;
            float2 fin;
            fin.x = my_noise + fw0;
            fin.y = my_noise + fw1;
            ((float2*)out)[idx] = fin;
        }
    }
}

extern "C" void kernel_launch(void* const* d_in, const int* in_sizes, int n_in,
                              void* d_out, int out_size, void* d_ws, size_t ws_size,
                              hipStream_t stream) {
    const float* x     = (const float*)d_in[0];
    // d_in[1] = context (unused by the reference)
    const float* eWih0 = (const float*)d_in[2];
    const float* eWhh0 = (const float*)d_in[3];
    const float* ebih0 = (const float*)d_in[4];
    const float* ebhh0 = (const float*)d_in[5];
    const float* eWih1 = (const float*)d_in[6];
    const float* eWhh1 = (const float*)d_in[7];
    const float* ebih1 = (const float*)d_in[8];
    const float* ebhh1 = (const float*)d_in[9];
    const float* dWih0 = (const float*)d_in[10];
    const float* dWhh0 = (const float*)d_in[11];
    const float* dbih0 = (const float*)d_in[12];
    const float* dbhh0 = (const float*)d_in[13];
    const float* dWih1 = (const float*)d_in[14];
    const float* dWhh1 = (const float*)d_in[15];
    const float* dbih1 = (const float*)d_in[16];
    const float* dbhh1 = (const float*)d_in[17];
    const float* fcW   = (const float*)d_in[18];
    const float* fcb   = (const float*)d_in[19];
    const float* outW  = (const float*)d_in[20];
    const float* outb  = (const float*)d_in[21];

    float* out = (float*)d_out;

    // 4096 elems x 16 lanes = 65536 threads = 1024 waves = 1 wave/SIMD
    fused_kernel<<<dim3((B_N * 16) / 256), dim3(256), 0, stream>>>(
        x, eWih0, eWhh0, ebih0, ebhh0, eWih1, eWhh1, ebih1, ebhh1,
        dWih0, dWhh0, dbih0, dbhh0, dWih1, dWhh1, dbih1, dbhh1,
        fcW, fcb, outW, outb, out);
}